// Round 1
// baseline (422.092 us; speedup 1.0000x reference)
//
#include <hip/hip_runtime.h>
#include <hip/hip_bf16.h>
#include <cstdint>

// Problem constants
constexpr int B_   = 64;
constexpr int L_   = 512;
constexpr int G_   = 128;
constexpr int N_   = 32;
constexpr int K_   = 8;
constexpr int E_   = 65536;
constexpr int DTOK = 64;
constexpr int H_   = 64;     // per-direction hidden
constexpr int NI   = 32;     // NTL_INP
constexpr int RH   = 256;    // NREL*NHID
constexpr int M_   = 2048;   // B*N distinct nodes
constexpr int JA   = 33;     // augmented j (32 + const-1 slot)
constexpr int COLS = RH * JA;   // 8448
constexpr int STRD = 36;        // padded row stride for hs/ht/a (float4-friendly)

#define DEV static __device__ __forceinline__

DEV float sigm(float x) { return 1.f / (1.f + __expf(-x)); }
DEV float tanh_fast(float x) {
    x = fminf(15.f, fmaxf(-15.f, x));
    float e = __expf(2.f * x);
    return (e - 1.f) / (e + 1.f);
}

// ---------------- K1: token embed + scatter-sum into groups -----------------
__global__ __launch_bounds__(256) void k_embed(const int* __restrict__ seq,
                                               const int* __restrict__ p2g,
                                               const float* __restrict__ emb,
                                               float* __restrict__ xg) {
    int gid = blockIdx.x * 256 + threadIdx.x;          // over B*L*64
    if (gid >= B_ * L_ * DTOK) return;
    int d  = gid & 63;
    int bl = gid >> 6;
    int b  = bl >> 9;                                   // /512
    int s  = seq[bl];
    int g  = p2g[bl];
    atomicAdd(&xg[((b << 7) + g) * 64 + d], emb[s * 64 + d]);
}

// ---------------- K1b: histograms of u and v --------------------------------
__global__ __launch_bounds__(256) void k_hist(const int* __restrict__ u,
                                              const int* __restrict__ v,
                                              int* __restrict__ cu, int* __restrict__ cv) {
    int n = blockIdx.x * 256 + threadIdx.x;
    if (n >= E_) return;
    atomicAdd(&cu[u[n]], 1);
    atomicAdd(&cv[v[n]], 1);
}

// ---------------- K_pre: input-gate GEMM (hoisted out of recurrence) --------
// pre[dir][b*G+s][gate] = x_grp[b,s,:] . w_ih[dir][gate,:] + b_ih + b_hh
__global__ __launch_bounds__(256) void k_pre(const float* __restrict__ xg,
                                             const float* __restrict__ wihf,
                                             const float* __restrict__ bihf,
                                             const float* __restrict__ bhhf,
                                             const float* __restrict__ wihb,
                                             const float* __restrict__ bihb,
                                             const float* __restrict__ bhhb,
                                             float* __restrict__ pre) {
    int dir = blockIdx.y;
    int t   = threadIdx.x;                               // gate 0..255
    const float* wih = dir ? wihb : wihf;
    float bias = dir ? (bihb[t] + bhhb[t]) : (bihf[t] + bhhf[t]);
    int r0 = blockIdx.x * 32;                            // rows of 8192 (b,s)

    float4 wv[16];
#pragma unroll
    for (int c = 0; c < 16; c++) wv[c] = ((const float4*)(wih + t * 64))[c];

    __shared__ __align__(16) float xs[32][68];
    for (int tix = t; tix < 32 * 16; tix += 256) {
        int r = tix >> 4, c = tix & 15;
        ((float4*)&xs[r][0])[c] = ((const float4*)(xg + (size_t)(r0 + r) * 64))[c];
    }
    __syncthreads();

    for (int ml = 0; ml < 32; ml++) {
        float acc = bias;
        const float4* xp = (const float4*)&xs[ml][0];
#pragma unroll
        for (int c = 0; c < 16; c++) {
            float4 x4 = xp[c];
            acc += x4.x * wv[c].x + x4.y * wv[c].y + x4.z * wv[c].z + x4.w * wv[c].w;
        }
        pre[((size_t)dir * 8192 + r0 + ml) * 256 + t] = acc;   // lanes=gate: coalesced
    }
}

// ---------------- K2: LSTM recurrence, one block per (dir, b) ---------------
__global__ __launch_bounds__(256) void k_lstm(const float* __restrict__ pre,
                                              const float* __restrict__ whh_f,
                                              const float* __restrict__ whh_b,
                                              float* __restrict__ hgrp) {
    int blk = blockIdx.x;                // 0..127
    int dir = blk >> 6;
    int b   = blk & 63;
    const float* whh = dir ? whh_b : whh_f;
    int t = threadIdx.x;                 // gate 0..255

    float4 wv[16];                       // W_hh row of this gate in registers
#pragma unroll
    for (int c = 0; c < 16; c++) wv[c] = ((const float4*)(whh + t * 64))[c];

    __shared__ __align__(16) float hl[64];
    __shared__ float cl[64];
    __shared__ float gl[256];
    if (t < 64) { hl[t] = 0.f; cl[t] = 0.f; }
    __syncthreads();

    const float* prow = pre + ((size_t)dir * 8192 + b * G_) * 256 + t;
    int s0 = dir ? (G_ - 1) : 0;
    float pnext = prow[(size_t)s0 * 256];

    for (int k = 0; k < G_; k++) {
        int s = dir ? (G_ - 1 - k) : k;
        float pcur = pnext;
        if (k + 1 < G_) {
            int sn = dir ? (G_ - 2 - k) : (k + 1);
            pnext = prow[(size_t)sn * 256];
        }
        float acc = pcur;
        const float4* hp = (const float4*)hl;
#pragma unroll
        for (int c = 0; c < 16; c++) {
            float4 h4 = hp[c];
            acc += h4.x * wv[c].x + h4.y * wv[c].y + h4.z * wv[c].z + h4.w * wv[c].w;
        }
        gl[t] = acc;
        __syncthreads();
        if (t < 64) {
            float gi = gl[t], gf = gl[64 + t], gg = gl[128 + t], go = gl[192 + t];
            float c2 = sigm(gf) * cl[t] + sigm(gi) * tanh_fast(gg);
            float hh = sigm(go) * tanh_fast(c2);
            cl[t] = c2; hl[t] = hh;
            hgrp[((size_t)b * G_ + s) * 128 + dir * 64 + t] = hh;
        }
        __syncthreads();
    }
}

// ---------------- K3: hierarchical gather + K-sum ---------------------------
__global__ __launch_bounds__(128) void k_gather(const int* __restrict__ idx,
                                                const int* __restrict__ p2g,
                                                const float* __restrict__ hgrp,
                                                float* __restrict__ hnode) {
    int m = blockIdx.x;          // 0..2047
    int d = threadIdx.x;         // 0..127
    int b = m >> 5;
    float acc = 0.f;
#pragma unroll
    for (int k = 0; k < K_; k++) {
        int l = idx[m * K_ + k];
        int g = p2g[b * L_ + l];
        acc += hgrp[((size_t)b * G_ + g) * 128 + d];
    }
    hnode[(size_t)m * 128 + d] = acc;
}

// ---------------- K4a: edge-endpoint projections on distinct nodes ----------
__global__ __launch_bounds__(256) void k_proj(const float* __restrict__ hnode,
                                              const float* __restrict__ wsrc,
                                              const float* __restrict__ bsrc,
                                              const float* __restrict__ wdst,
                                              const float* __restrict__ bdst,
                                              float* __restrict__ Ps, float* __restrict__ Pd) {
    __shared__ __align__(16) float hsl[8][132];
    __shared__ __align__(16) float wsl[32][132];
    __shared__ __align__(16) float wdl[32][132];
    int m0 = blockIdx.x * 8;
    int t  = threadIdx.x;
    for (int tix = t; tix < 8 * 32; tix += 256) {
        int r = tix >> 5, c = tix & 31;
        ((float4*)&hsl[r][0])[c] = ((const float4*)(hnode + (size_t)(m0 + r) * 128))[c];
    }
    for (int tix = t; tix < 32 * 32; tix += 256) {
        int r = tix >> 5, c = tix & 31;
        ((float4*)&wsl[r][0])[c] = ((const float4*)(wsrc + (size_t)r * 128))[c];
        ((float4*)&wdl[r][0])[c] = ((const float4*)(wdst + (size_t)r * 128))[c];
    }
    __syncthreads();
    int ml = t >> 5, o = t & 31;
    float accS = bsrc[o], accD = bdst[o];
    const float4* hp = (const float4*)&hsl[ml][0];
    const float4* sp = (const float4*)&wsl[o][0];
    const float4* dp = (const float4*)&wdl[o][0];
#pragma unroll
    for (int c = 0; c < 32; c++) {
        float4 h4 = hp[c], s4 = sp[c], d4 = dp[c];
        accS += h4.x * s4.x + h4.y * s4.y + h4.z * s4.z + h4.w * s4.w;
        accD += h4.x * d4.x + h4.y * d4.y + h4.z * d4.z + h4.w * d4.w;
    }
    Ps[(size_t)(m0 + ml) * 32 + o] = accS;
    Pd[(size_t)(m0 + ml) * 32 + o] = accD;
}

// ---------------- K4b: count-weighted BatchNorm stats -----------------------
__global__ __launch_bounds__(1024) void k_bnstat(const float* __restrict__ Ps,
                                                 const float* __restrict__ Pd,
                                                 const int* __restrict__ cu,
                                                 const int* __restrict__ cv,
                                                 float* __restrict__ bnout) {
    int side = blockIdx.x;
    const float* P  = side ? Pd : Ps;
    const int*   cn = side ? cv : cu;
    int t  = threadIdx.x;
    int mp = t >> 5, o = t & 31;
    float s1 = 0.f, s2 = 0.f;
    for (int m = mp; m < M_; m += 32) {
        float c = (float)cn[m];
        float x = P[(size_t)m * 32 + o];
        s1 += c * x;
        s2 += c * x * x;
    }
    __shared__ float r1[1024], r2[1024];
    r1[t] = s1; r2[t] = s2;
    __syncthreads();
    for (int off = 512; off >= 32; off >>= 1) {
        if (t < off) { r1[t] += r1[t + off]; r2[t] += r2[t + off]; }
        __syncthreads();
    }
    if (t < 32) {
        float mu  = r1[t] / (float)E_;
        float var = r2[t] / (float)E_ - mu * mu;
        bnout[side * 64 + t]      = mu;
        bnout[side * 64 + 32 + t] = rsqrtf(var + 1e-5f);
    }
}

// ---------------- K5n: normalize + build augmented hs/ht --------------------
__global__ __launch_bounds__(256) void k_norm(const float* __restrict__ Ps,
                                              const float* __restrict__ Pd,
                                              const float* __restrict__ bnout,
                                              const float* __restrict__ gs,
                                              const float* __restrict__ bes,
                                              const float* __restrict__ gd,
                                              const float* __restrict__ bed,
                                              float* __restrict__ hsaug,
                                              float* __restrict__ htaug) {
    int gid = blockIdx.x * 256 + threadIdx.x;
    if (gid >= M_ * 2 * STRD) return;
    int m = gid / (2 * STRD), s2 = gid % (2 * STRD);
    if (s2 < STRD) {
        int i = s2;
        float val = (i < 32) ? (gs[i] * (Ps[(size_t)m * 32 + i] - bnout[i]) * bnout[32 + i] + bes[i])
                             : ((i == 32) ? 1.f : 0.f);
        hsaug[(size_t)m * STRD + i] = val;
    } else {
        int j = s2 - STRD;
        float val = (j < 32) ? (gd[j] * (Pd[(size_t)m * 32 + j] - bnout[64 + j]) * bnout[96 + j] + bed[j])
                             : ((j == 32) ? 1.f : 0.f);
        htaug[(size_t)m * STRD + j] = val;
    }
}

// ---------------- K5a: build augmented W (ntl_w | ntl_v-src | ntl_b) --------
// waug[i][rh*33+j], i=0..32.  i<32,j<32: ntl_w[rh,i,j]; i<32,j=32: ntl_v[rh,i];
// i=32: j=32 -> ntl_b[rh], else 0.  (pairs with hsaug[...,32]=1)
__global__ __launch_bounds__(256) void k_waug(const float* __restrict__ ntlw,
                                              const float* __restrict__ ntlv,
                                              const float* __restrict__ ntlb,
                                              float* __restrict__ waug) {
    int gid = blockIdx.x * 256 + threadIdx.x;
    if (gid >= JA * COLS) return;
    int i   = gid / COLS;
    int col = gid - i * COLS;
    int rh  = col / JA;
    int j   = col - rh * JA;
    float val;
    if (i < 32) val = (j < 32) ? ntlw[((size_t)rh * 32 + i) * 32 + j] : ntlv[rh * 64 + i];
    else        val = (j == 32) ? ntlb[rh] : 0.f;
    waug[gid] = val;
}

// ---------------- K5b: A[m][rh*33+j] = sum_i hsaug[m,i]*waug[i][col] --------
__global__ __launch_bounds__(256) void k_agemm(const float* __restrict__ hsaug,
                                               const float* __restrict__ waug,
                                               __hip_bfloat16* __restrict__ A) {
    int mt  = blockIdx.x;                  // 64 tiles of 32 m
    int ct  = blockIdx.y;                  // 33 tiles of 256 cols
    int col = ct * 256 + threadIdx.x;      // COLS = 33*256 exactly
    float w[JA];
#pragma unroll
    for (int i = 0; i < JA; i++) w[i] = waug[(size_t)i * COLS + col];

    __shared__ __align__(16) float hs[32][STRD];
    for (int tix = threadIdx.x; tix < 32 * 9; tix += 256) {
        int r = tix / 9, c = tix - r * 9;
        ((float4*)&hs[r][0])[c] = ((const float4*)(hsaug + (size_t)(mt * 32 + r) * STRD))[c];
    }
    __syncthreads();
#pragma unroll 1
    for (int ml = 0; ml < 32; ml++) {
        float acc = 0.f;
#pragma unroll
        for (int i = 0; i < JA; i++) acc += hs[ml][i] * w[i];
        A[(size_t)(mt * 32 + ml) * COLS + col] = __float2bfloat16(acc);
    }
}

// ---------------- K5c: Ldst[m][rh] = sum_j ntl_v[rh,32+j]*ht[m,j] -----------
__global__ __launch_bounds__(256) void k_ldst(const float* __restrict__ htaug,
                                              const float* __restrict__ ntlv,
                                              float* __restrict__ Ldst) {
    int m0 = blockIdx.x * 8;
    int rh = threadIdx.x;
    __shared__ __align__(16) float ht[8][STRD];
    for (int tix = threadIdx.x; tix < 8 * 9; tix += 256) {
        int r = tix / 9, c = tix - r * 9;
        ((float4*)&ht[r][0])[c] = ((const float4*)(htaug + (size_t)(m0 + r) * STRD))[c];
    }
    float w[32];
#pragma unroll
    for (int j = 0; j < 32; j++) w[j] = ntlv[rh * 64 + 32 + j];
    __syncthreads();
    for (int ml = 0; ml < 8; ml++) {
        float acc = 0.f;
#pragma unroll
        for (int j = 0; j < 32; j++) acc += ht[ml][j] * w[j];
        Ldst[(size_t)(m0 + ml) * 256 + rh] = acc;
    }
}

// ---------------- K_scan: exclusive prefix over cnt_u (2048 bins) -----------
__global__ __launch_bounds__(1024) void k_scan(const int* __restrict__ cu,
                                               int* __restrict__ ustart,
                                               int* __restrict__ ucursor) {
    __shared__ int s[2048];
    int t  = threadIdx.x;
    int c0 = cu[t], c1 = cu[t + 1024];
    s[t] = c0; s[t + 1024] = c1;
    __syncthreads();
    for (int off = 1; off < 2048; off <<= 1) {
        int a0 = (t >= off) ? s[t - off] : 0;
        int a1 = ((t + 1024) >= off) ? s[t + 1024 - off] : 0;
        __syncthreads();
        s[t] += a0; s[t + 1024] += a1;
        __syncthreads();
    }
    int e0 = s[t] - c0, e1 = s[t + 1024] - c1;
    ustart[t] = e0;            ustart[t + 1024] = e1;
    ucursor[t] = e0;           ucursor[t + 1024] = e1;
    if (t == 0) ustart[2048] = E_;
}

// ---------------- K_scatter: counting-sort edges by u -----------------------
__global__ __launch_bounds__(256) void k_scatter(const int* __restrict__ u,
                                                 int* __restrict__ ucursor,
                                                 int* __restrict__ eorder) {
    int n = blockIdx.x * 256 + threadIdx.x;
    if (n >= E_) return;
    int pos = atomicAdd(&ucursor[u[n]], 1);
    eorder[pos] = n;
}

// ---------------- K6: z[n][rh] = A[u].ht_aug[v] + Ldst[v][rh]; LN stats -----
__global__ __launch_bounds__(256, 2) void k_z(const __hip_bfloat16* __restrict__ A,
                                              const float* __restrict__ htaug,
                                              const float* __restrict__ Ldst,
                                              const int* __restrict__ ustart,
                                              const int* __restrict__ eorder,
                                              const int* __restrict__ v,
                                              __hip_bfloat16* __restrict__ z,
                                              float* __restrict__ zsum,
                                              float* __restrict__ zsq) {
    __shared__ __align__(16) float al[256 * STRD];
    __shared__ __align__(16) float htl[32][STRD];
    __shared__ int nnl[32], vvl[32];
    int t = threadIdx.x;
    // zero pads of al once (never written by staging)
    al[t * STRD + 33] = 0.f; al[t * STRD + 34] = 0.f; al[t * STRD + 35] = 0.f;
    float s1 = 0.f, s2 = 0.f;

    for (int ui = 0; ui < 4; ui++) {
        int uu = blockIdx.x * 4 + ui;
        __syncthreads();                        // protect al reuse
        // stage A row (coalesced bf16) -> LDS f32, layout [rh][STRD]
        for (int k = 0; k < JA; k++) {
            int idx2 = k * 256 + t;             // 0..8447
            int rh = idx2 / JA, j = idx2 - rh * JA;
            al[rh * STRD + j] = __bfloat162float(A[(size_t)uu * COLS + idx2]);
        }
        __syncthreads();
        float4 av4[9];
#pragma unroll
        for (int c = 0; c < 9; c++) av4[c] = ((const float4*)&al[t * STRD])[c];

        int e0 = ustart[uu], e1 = ustart[uu + 1];
        for (int eb = e0; eb < e1; eb += 32) {
            int nb = min(32, e1 - eb);
            __syncthreads();                    // protect htl/vvl reuse
            if (t < nb) { int n = eorder[eb + t]; nnl[t] = n; vvl[t] = v[n]; }
            __syncthreads();
            for (int tix = t; tix < nb * 9; tix += 256) {
                int e = tix / 9, c = tix - e * 9;
                ((float4*)&htl[e][0])[c] = ((const float4*)(htaug + (size_t)vvl[e] * STRD))[c];
            }
            __syncthreads();
            for (int e = 0; e < nb; e++) {
                float acc = Ldst[(size_t)vvl[e] * 256 + t];
                const float4* hp = (const float4*)&htl[e][0];
#pragma unroll
                for (int c = 0; c < 9; c++) {
                    float4 h4 = hp[c];
                    acc += av4[c].x * h4.x + av4[c].y * h4.y + av4[c].z * h4.z + av4[c].w * h4.w;
                }
                z[(size_t)nnl[e] * 256 + t] = __float2bfloat16(acc);
                s1 += acc; s2 += acc * acc;
            }
        }
    }
    atomicAdd(&zsum[t], s1);
    atomicAdd(&zsq[t], s2);
}

// ---------------- K7: finalize LayerNorm stats ------------------------------
__global__ __launch_bounds__(256) void k_lnfin(const float* __restrict__ zsum,
                                               const float* __restrict__ zsq,
                                               float* __restrict__ zstat) {
    int t = threadIdx.x;
    float mu  = zsum[t] / (float)E_;
    float var = zsq[t] / (float)E_ - mu * mu;
    zstat[t]       = mu;
    zstat[256 + t] = rsqrtf(var + 1e-5f);
}

// ---------------- K8: LN + tanh + contract to logits ------------------------
__global__ __launch_bounds__(256) void k_logit(const __hip_bfloat16* __restrict__ z,
                                               const float* __restrict__ zstat,
                                               const float* __restrict__ ntlu,
                                               const float* __restrict__ ntlg,
                                               const float* __restrict__ ntlbe,
                                               float* __restrict__ out) {
    int t  = threadIdx.x;                 // rh = r*16+h
    int n0 = blockIdx.x * 16;
    float mu  = zstat[t], isd = zstat[256 + t];
    float g   = ntlg[t],  be  = ntlbe[t];
    float uw  = ntlu[t];                  // ntl_u[r,0,h] flat = rh
    float zv[16];
#pragma unroll
    for (int nl = 0; nl < 16; nl++)
        zv[nl] = __bfloat162float(z[(size_t)(n0 + nl) * 256 + t]);
#pragma unroll 1
    for (int nl = 0; nl < 16; nl++) {
        float zn  = g * (zv[nl] - mu) * isd + be;
        float val = uw * tanhf(zn);
        val += __shfl_xor(val, 1);
        val += __shfl_xor(val, 2);
        val += __shfl_xor(val, 4);
        val += __shfl_xor(val, 8);
        if ((t & 15) == 0) out[(size_t)(n0 + nl) * 16 + (t >> 4)] = val;
    }
}

// ============================ host side =====================================
extern "C" void kernel_launch(void* const* d_in, const int* in_sizes, int n_in,
                              void* d_out, int out_size, void* d_ws, size_t ws_size,
                              hipStream_t stream) {
    const int*   seq   = (const int*)d_in[0];
    const int*   p2g   = (const int*)d_in[1];
    const int*   idx   = (const int*)d_in[2];
    const int*   u     = (const int*)d_in[3];
    const int*   v     = (const int*)d_in[4];
    const float* emb   = (const float*)d_in[5];
    const float* wihf  = (const float*)d_in[6];
    const float* whhf  = (const float*)d_in[7];
    const float* bihf  = (const float*)d_in[8];
    const float* bhhf  = (const float*)d_in[9];
    const float* wihb  = (const float*)d_in[10];
    const float* whhb  = (const float*)d_in[11];
    const float* bihb  = (const float*)d_in[12];
    const float* bhhb  = (const float*)d_in[13];
    const float* wsrc  = (const float*)d_in[14];
    const float* bsrc  = (const float*)d_in[15];
    const float* wdst  = (const float*)d_in[16];
    const float* bdst  = (const float*)d_in[17];
    const float* gs    = (const float*)d_in[18];
    const float* bes   = (const float*)d_in[19];
    const float* gd    = (const float*)d_in[20];
    const float* bed   = (const float*)d_in[21];
    const float* ntlw  = (const float*)d_in[22];
    const float* ntlv  = (const float*)d_in[23];
    const float* ntlb  = (const float*)d_in[24];
    const float* ntlu  = (const float*)d_in[25];
    const float* ntlg  = (const float*)d_in[26];
    const float* ntlbe = (const float*)d_in[27];
    float* out = (float*)d_out;

    char* ws = (char*)d_ws;
    size_t off = 0;
    auto take = [&](size_t bytes) -> char* {
        char* p = ws + off;
        off = (off + bytes + 255) & ~(size_t)255;
        return p;
    };
    // zeroed region (contiguous, one memset)
    float* x_grp  = (float*)take((size_t)B_ * G_ * 64 * 4);
    int*   cnt_u  = (int*)  take(2048 * 4);
    int*   cnt_v  = (int*)  take(2048 * 4);
    float* zsum   = (float*)take(256 * 4);
    float* zsq    = (float*)take(256 * 4);
    size_t zero_bytes = off;
    // rest
    int*   ucursor = (int*)  take(2048 * 4);
    int*   ustart  = (int*)  take(2049 * 4);
    int*   eorder  = (int*)  take((size_t)E_ * 4);
    float* pre     = (float*)take((size_t)2 * 8192 * 256 * 4);
    float* hgrp    = (float*)take((size_t)B_ * G_ * 128 * 4);
    float* hnode   = (float*)take((size_t)M_ * 128 * 4);
    float* Psrc    = (float*)take((size_t)M_ * 32 * 4);
    float* Pdst    = (float*)take((size_t)M_ * 32 * 4);
    float* bnout   = (float*)take(128 * 4);
    float* hsaug   = (float*)take((size_t)M_ * STRD * 4);
    float* htaug   = (float*)take((size_t)M_ * STRD * 4);
    float* waug    = (float*)take((size_t)JA * COLS * 4);
    float* LdstB   = (float*)take((size_t)M_ * 256 * 4);
    float* zstat   = (float*)take(512 * 4);
    __hip_bfloat16* Abuf = (__hip_bfloat16*)take((size_t)M_ * COLS * 2);
    __hip_bfloat16* zbuf = (__hip_bfloat16*)take((size_t)E_ * 256 * 2);
    (void)ws_size; (void)in_sizes; (void)n_in; (void)out_size;

    hipMemsetAsync(d_ws, 0, zero_bytes, stream);

    k_embed<<<(B_ * L_ * DTOK) / 256, 256, 0, stream>>>(seq, p2g, emb, x_grp);
    k_hist<<<E_ / 256, 256, 0, stream>>>(u, v, cnt_u, cnt_v);
    k_pre<<<dim3(256, 2), 256, 0, stream>>>(x_grp, wihf, bihf, bhhf, wihb, bihb, bhhb, pre);
    k_lstm<<<128, 256, 0, stream>>>(pre, whhf, whhb, hgrp);
    k_gather<<<M_, 128, 0, stream>>>(idx, p2g, hgrp, hnode);
    k_proj<<<M_ / 8, 256, 0, stream>>>(hnode, wsrc, bsrc, wdst, bdst, Psrc, Pdst);
    k_bnstat<<<2, 1024, 0, stream>>>(Psrc, Pdst, cnt_u, cnt_v, bnout);
    k_norm<<<(M_ * 2 * STRD + 255) / 256, 256, 0, stream>>>(Psrc, Pdst, bnout, gs, bes, gd, bed, hsaug, htaug);
    k_waug<<<(JA * COLS + 255) / 256, 256, 0, stream>>>(ntlw, ntlv, ntlb, waug);
    k_agemm<<<dim3(M_ / 32, JA), 256, 0, stream>>>(hsaug, waug, Abuf);
    k_ldst<<<M_ / 8, 256, 0, stream>>>(htaug, ntlv, LdstB);
    k_scan<<<1, 1024, 0, stream>>>(cnt_u, ustart, ucursor);
    k_scatter<<<E_ / 256, 256, 0, stream>>>(u, ucursor, eorder);
    k_z<<<M_ / 4, 256, 0, stream>>>(Abuf, htaug, LdstB, ustart, eorder, v, zbuf, zsum, zsq);
    k_lnfin<<<1, 256, 0, stream>>>(zsum, zsq, zstat);
    k_logit<<<E_ / 16, 256, 0, stream>>>(zbuf, zstat, ntlu, ntlg, ntlbe, out);
}